// Round 3
// baseline (357.517 us; speedup 1.0000x reference)
//
#include <hip/hip_runtime.h>
#include <stdint.h>

// out = x @ tanh(block_diag(blocks)) -- 16 blocks of 256x256. ALL BUFFERS FLOAT32.
// Kernel 1: pack tanh'd diagonal blocks transposed -> bf16 wsT[j][n][k] (2 MB in d_ws).
// Kernel 2: barrier-free streaming GEMM. Per wave: B-block fragments live in 128 VGPRs
//           (loaded once), then stream 16-row m-steps: global loads -> cvt -> MFMA -> store.

typedef float floatx4 __attribute__((ext_vector_type(4)));
typedef __bf16 bf16x8 __attribute__((ext_vector_type(8)));

#define LDX 4096
#define NBLK 16
#define BS 256
#define WPJ 32     // m-slabs (WGs per block column)
#define MSTEPS 16  // m-steps per WG
#define MROWS 16   // rows per m-step (one MFMA M)

__device__ __forceinline__ unsigned int f2bf(float f) {
  union { float f; unsigned int i; } x;
  x.f = f;
  unsigned int r = x.i + 0x7FFFu + ((x.i >> 16) & 1u);  // RNE
  return r >> 16;
}

__device__ __forceinline__ bf16x8 cvt8(float4 a, float4 b) {
  union { unsigned int u[4]; bf16x8 v; } r;
  r.u[0] = f2bf(a.x) | (f2bf(a.y) << 16);
  r.u[1] = f2bf(a.z) | (f2bf(a.w) << 16);
  r.u[2] = f2bf(b.x) | (f2bf(b.y) << 16);
  r.u[3] = f2bf(b.z) | (f2bf(b.w) << 16);
  return r.v;
}

// wsT[j*65536 + n*256 + k] = tanh(blocks[(j*256+k)*4096 + j*256 + n]), stored bf16.
__global__ __launch_bounds__(256) void tanh_pack(const float* __restrict__ blocks,
                                                 unsigned short* __restrict__ wsT) {
  __shared__ float tile[64][65];  // [k][n], +1 pad for conflict-free column reads
  const int t = threadIdx.x;
  const int tc = blockIdx.x, tr = blockIdx.y, j = blockIdx.z;
  const float* src = blocks + (size_t)(j * BS + tr * 64) * LDX + j * BS + tc * 64;
#pragma unroll
  for (int it = 0; it < 8; ++it) {
    int v = it * 256 + t;
    int row = v >> 5;       // k within tile
    int c2 = (v & 31) * 2;  // n within tile, even
    float2 f = *(const float2*)(src + (size_t)row * LDX + c2);
    tile[row][c2] = tanhf(f.x);
    tile[row][c2 + 1] = tanhf(f.y);
  }
  __syncthreads();
  unsigned short* dst = wsT + (size_t)j * BS * BS + (size_t)(tc * 64) * BS + tr * 64;
#pragma unroll
  for (int it = 0; it < 8; ++it) {
    int v = it * 256 + t;
    int nn = v >> 5;        // n within tile
    int k2 = (v & 31) * 2;  // k within tile, even
    unsigned int pair = f2bf(tile[k2][nn]) | (f2bf(tile[k2 + 1][nn]) << 16);
    *(unsigned int*)(dst + (size_t)nn * BS + k2) = pair;
  }
}

// Barrier-free streaming GEMM. grid = (WPJ, NBLK), 256 threads (4 waves).
// Wave w owns n-slab [w*64, w*64+64) of block j; B frags resident in VGPRs.
__global__ __launch_bounds__(256, 2) void bdgemm_stream(const float* __restrict__ x,
                                                        const unsigned short* __restrict__ wsT,
                                                        float* __restrict__ out) {
  const int t = threadIdx.x;
  const int lane = t & 63;
  const int wave = t >> 6;
  const int mslab = blockIdx.x;  // 0..WPJ-1
  const int j = blockIdx.y;      // 0..15
  const int fr = lane & 15;        // MFMA m/n index
  const int fq = (lane >> 4) * 8;  // MFMA k sub-offset within 32-window
  const int n0w = wave * 64;
  const int r0 = (lane >> 4) * 4;  // C/D row base (m89-verified mapping)

  // ---- B fragments, loaded once: B[n0w+nf*16+fr][kw*32+fq .. +7], 128 VGPRs ----
  const unsigned short* wb = wsT + (size_t)j * (BS * BS);
  bf16x8 Bf[8][4];
#pragma unroll
  for (int kw = 0; kw < 8; ++kw)
#pragma unroll
    for (int nf = 0; nf < 4; ++nf)
      Bf[kw][nf] = *(const bf16x8*)(wb + (size_t)(n0w + nf * 16 + fr) * BS + kw * 32 + fq);

  const int col0 = j * BS + n0w + fr;
  for (int step = 0; step < MSTEPS; ++step) {
    const int m0 = (mslab * MSTEPS + step) * MROWS;
    const float* ax = x + (size_t)(m0 + fr) * LDX + j * BS + fq;

    floatx4 acc[4];
#pragma unroll
    for (int nf = 0; nf < 4; ++nf) acc[nf] = (floatx4){0.f, 0.f, 0.f, 0.f};

#pragma unroll
    for (int kw = 0; kw < 8; ++kw) {
      // A[m=fr][k = kw*32+fq .. +7] : two float4 loads, pack to bf16x8
      float4 f0 = *(const float4*)(ax + kw * 32);
      float4 f1 = *(const float4*)(ax + kw * 32 + 4);
      bf16x8 av = cvt8(f0, f1);
#pragma unroll
      for (int nf = 0; nf < 4; ++nf)
        acc[nf] = __builtin_amdgcn_mfma_f32_16x16x32_bf16(av, Bf[kw][nf], acc[nf], 0, 0, 0);
    }

    // C/D: col = lane&15, row = (lane>>4)*4 + reg
#pragma unroll
    for (int nf = 0; nf < 4; ++nf) {
      float* op = out + (size_t)(m0 + r0) * LDX + col0 + nf * 16;
#pragma unroll
      for (int r = 0; r < 4; ++r) op[(size_t)r * LDX] = acc[nf][r];
    }
  }
}

// Fallback (ws too small): one-kernel fused path, tanh applied during B staging.
__global__ __launch_bounds__(256) void bdgemm_fused(const float* __restrict__ x,
                                                    const float* __restrict__ blocks,
                                                    float* __restrict__ out) {
  __shared__ unsigned short As[64 * 32];
  __shared__ unsigned short Bs[256 * 40];
  const int t = threadIdx.x;
  const int lane = t & 63;
  const int wave = t >> 6;
  const int mtile = blockIdx.x;
  const int j = blockIdx.y;
  const int m0 = mtile * 64;
  const float* xg = x + (size_t)m0 * LDX + j * BS;
  const int srow = t >> 2;
  const int scol = (t & 3) * 8;
  const int wn = wave * 64;
  const int fr = lane & 15;
  const int fq = (lane >> 4) * 8;

  floatx4 acc[4][4];
#pragma unroll
  for (int a = 0; a < 4; ++a)
#pragma unroll
    for (int b = 0; b < 4; ++b) acc[a][b] = (floatx4){0.f, 0.f, 0.f, 0.f};

  for (int kt = 0; kt < 8; ++kt) {
    const int k0 = kt * 32;
    const float* ap = xg + (size_t)srow * LDX + k0 + scol;
    float4 a0 = *(const float4*)(ap);
    float4 a1 = *(const float4*)(ap + 4);
    uint4 pk;
    pk.x = f2bf(a0.x) | (f2bf(a0.y) << 16);
    pk.y = f2bf(a0.z) | (f2bf(a0.w) << 16);
    pk.z = f2bf(a1.x) | (f2bf(a1.y) << 16);
    pk.w = f2bf(a1.z) | (f2bf(a1.w) << 16);
    *(uint4*)(As + t * 8) = pk;
#pragma unroll
    for (int i = 0; i < 32; ++i) {
      const int idx = i * 256 + t;
      const int kk = idx >> 8;
      const int nn = idx & 255;
      float v = tanhf(blocks[(size_t)(j * BS + k0 + kk) * LDX + j * BS + nn]);
      Bs[nn * 40 + kk] = (unsigned short)f2bf(v);
    }
    __syncthreads();
    bf16x8 af[4], bfm[4];
#pragma unroll
    for (int i = 0; i < 4; ++i) {
      af[i] = *(const bf16x8*)(As + (i * 16 + fr) * 32 + fq);
      bfm[i] = *(const bf16x8*)(Bs + (wn + i * 16 + fr) * 40 + fq);
    }
#pragma unroll
    for (int mi = 0; mi < 4; ++mi)
#pragma unroll
      for (int ni = 0; ni < 4; ++ni)
        acc[mi][ni] =
            __builtin_amdgcn_mfma_f32_16x16x32_bf16(af[mi], bfm[ni], acc[mi][ni], 0, 0, 0);
    __syncthreads();
  }
  const int r0 = (lane >> 4) * 4;
  const int ocol = j * BS + wn + fr;
#pragma unroll
  for (int mi = 0; mi < 4; ++mi)
#pragma unroll
    for (int ni = 0; ni < 4; ++ni) {
      float* op = out + (size_t)(m0 + mi * 16 + r0) * LDX + ocol + ni * 16;
#pragma unroll
      for (int r = 0; r < 4; ++r) op[(size_t)r * LDX] = acc[mi][ni][r];
    }
}

extern "C" void kernel_launch(void* const* d_in, const int* in_sizes, int n_in,
                              void* d_out, int out_size, void* d_ws, size_t ws_size,
                              hipStream_t stream) {
  const float* x = (const float*)d_in[0];       // 8192x4096 f32
  const float* blocks = (const float*)d_in[1];  // 4096x4096 f32
  // d_in[2] (mask) unused: block structure static, tanh(0)=0.
  float* out = (float*)d_out;

  const size_t need = (size_t)NBLK * BS * BS * sizeof(unsigned short);  // 2 MB
  if (d_ws != nullptr && ws_size >= need) {
    unsigned short* wsT = (unsigned short*)d_ws;
    tanh_pack<<<dim3(4, 4, NBLK), 256, 0, stream>>>(blocks, wsT);
    bdgemm_stream<<<dim3(WPJ, NBLK), 256, 0, stream>>>(x, wsT, out);
  } else {
    bdgemm_fused<<<dim3(128, NBLK), 256, 0, stream>>>(x, blocks, out);
  }
}

// Round 4
// 326.371 us; speedup vs baseline: 1.0954x; 1.0954x over previous
//
#include <hip/hip_runtime.h>
#include <stdint.h>

// out = x @ tanh(block_diag(blocks)) -- 16 blocks of 256x256. ALL BUFFERS FLOAT32.
// tanh_pack: diagonal blocks -> bf16 wsT[j][n][k] (2 MB in d_ws).
// bdgemm_pipe: per-WG LDS-DMA ring pipeline. B resident in regs/AGPRs, A streamed
//   global->LDS via 3-deep global_load_lds ring, raw s_barrier + manual vmcnt
//   (never vmcnt(0)) so DMA stays in flight across steps. No __syncthreads.

typedef float floatx4 __attribute__((ext_vector_type(4)));
typedef __bf16 bf16x8 __attribute__((ext_vector_type(8)));

#define LDX 4096
#define NBLK 16
#define BS 256
#define WPJ 32     // WGs per block column
#define MSTEPS 16  // m-steps per WG (16 rows each)

// s_waitcnt imm encodings (gfx9): vmcnt[3:0]|[15:14], exp[6:4]=7, lgkm[11:8]=15
#define VMW8 0x0F78   // vmcnt(8)
#define VMW24 0x4F78  // vmcnt(24)
#define VMW40 0x8F78  // vmcnt(40)
#define LGKM0 0xC07F  // lgkmcnt(0), vmcnt unconstrained

__device__ __forceinline__ unsigned int f2bf(float f) {
  union { float f; unsigned int i; } x;
  x.f = f;
  unsigned int r = x.i + 0x7FFFu + ((x.i >> 16) & 1u);  // RNE
  return r >> 16;
}

__device__ __forceinline__ bf16x8 cvt8(float4 a, float4 b) {
  union { unsigned int u[4]; bf16x8 v; } r;
  r.u[0] = f2bf(a.x) | (f2bf(a.y) << 16);
  r.u[1] = f2bf(a.z) | (f2bf(a.w) << 16);
  r.u[2] = f2bf(b.x) | (f2bf(b.y) << 16);
  r.u[3] = f2bf(b.z) | (f2bf(b.w) << 16);
  return r.v;
}

__device__ __forceinline__ void async_copy16(const void* g, void* l) {
  __builtin_amdgcn_global_load_lds(
      (__attribute__((address_space(1))) void*)(uintptr_t)g,
      (__attribute__((address_space(3))) void*)(unsigned int)(uintptr_t)l,
      16, 0, 0);
}

// wsT[j*65536 + n*256 + k] = tanh(blocks[(j*256+k)*4096 + j*256 + n]), stored bf16.
__global__ __launch_bounds__(256) void tanh_pack(const float* __restrict__ blocks,
                                                 unsigned short* __restrict__ wsT) {
  __shared__ float tile[64][65];
  const int t = threadIdx.x;
  const int tc = blockIdx.x, tr = blockIdx.y, j = blockIdx.z;
  const float* src = blocks + (size_t)(j * BS + tr * 64) * LDX + j * BS + tc * 64;
#pragma unroll
  for (int it = 0; it < 8; ++it) {
    int v = it * 256 + t;
    int row = v >> 5;
    int c2 = (v & 31) * 2;
    float2 f = *(const float2*)(src + (size_t)row * LDX + c2);
    tile[row][c2] = tanhf(f.x);
    tile[row][c2 + 1] = tanhf(f.y);
  }
  __syncthreads();
  unsigned short* dst = wsT + (size_t)j * BS * BS + (size_t)(tc * 64) * BS + tr * 64;
#pragma unroll
  for (int it = 0; it < 8; ++it) {
    int v = it * 256 + t;
    int nn = v >> 5;
    int k2 = (v & 31) * 2;
    unsigned int pair = f2bf(tile[k2][nn]) | (f2bf(tile[k2 + 1][nn]) << 16);
    *(unsigned int*)(dst + (size_t)nn * BS + k2) = pair;
  }
}

// LDS A layout per buffer: float idx = kc*64 + row*4 + c  (kc = 16B chunk 0..63, row 0..15)
// -> DMA instr (w,q) writes bytes [(w*4+q)*1024, +1024) = 4 kc x 16 rows, lane-contiguous.
// -> ds_read_b128 at [kc*64 + fr*4]: banks = fr*4 mod 32, ~2-way within 16-lane phase.
__global__ __launch_bounds__(256, 2) void bdgemm_pipe(const float* __restrict__ x,
                                                      const unsigned short* __restrict__ wsT,
                                                      float* __restrict__ out) {
  __shared__ float abuf[3][4096];  // 3-deep ring, 16 KB each
  const int t = threadIdx.x;
  const int lane = t & 63;
  const int wave = t >> 6;
  const int mslab = blockIdx.x;  // 0..WPJ-1
  const int j = blockIdx.y;      // 0..15
  const int fr = lane & 15;
  const int fqg = lane >> 4;       // 0..3
  const int n0w = wave * 64;
  const int r0 = fqg * 4;          // C/D row base (m89-verified mapping)
  const int mbase = mslab * (MSTEPS * 16);

  // ---- B fragments, loaded once: 128 regs (compiler may place in AGPRs) ----
  const unsigned short* wb = wsT + (size_t)j * (BS * BS);
  bf16x8 Bf[8][4];
#pragma unroll
  for (int kw = 0; kw < 8; ++kw)
#pragma unroll
    for (int nf = 0; nf < 4; ++nf)
      Bf[kw][nf] = *(const bf16x8*)(wb + (size_t)(n0w + nf * 16 + fr) * BS + kw * 32 + fqg * 8);

  // DMA issue: this wave's 4 KB share of step s into ring buffer b.
  auto issue = [&](int s, int b) {
    const float* g = x + (size_t)(mbase + s * 16 + fr) * LDX + j * BS;
    char* l = (char*)&abuf[b][0];
#pragma unroll
    for (int q = 0; q < 4; ++q) {
      const int kc = (wave * 4 + q) * 4 + fqg;  // 16B chunk index 0..63
      async_copy16(g + kc * 4, l + (wave * 4 + q) * 1024 + lane * 16);
    }
  };

  issue(0, 0);
  issue(1, 1);
  issue(2, 2);

  const int col0 = j * BS + n0w + fr;
  for (int s = 0; s < MSTEPS; ++s) {
    // Wait for own share of step s (in-order vmcnt retire; allow = ops issued after it:
    // s=0: L1,L2=8; s=1: +S0,L3=24; s>=2: two loads + two store batches = 40).
    if (s == 0) __builtin_amdgcn_s_waitcnt(VMW8);
    else if (s == 1) __builtin_amdgcn_s_waitcnt(VMW24);
    else __builtin_amdgcn_s_waitcnt(VMW40);
    __builtin_amdgcn_s_barrier();  // raw: no counter drain; buffer s now fully valid

    const int b = s % 3;
    const float* ab = &abuf[b][0];
    bf16x8 av[8];
#pragma unroll
    for (int kw = 0; kw < 8; ++kw) {
      const int kc0 = kw * 8 + fqg * 2;
      float4 f0 = *(const float4*)(ab + kc0 * 64 + fr * 4);
      float4 f1 = *(const float4*)(ab + (kc0 + 1) * 64 + fr * 4);
      av[kw] = cvt8(f0, f1);  // A[m=fr][k=kw*32+fqg*8 ..+7] as bf16
    }
    __builtin_amdgcn_s_waitcnt(LGKM0);  // all ds_reads landed in regs
    __builtin_amdgcn_s_barrier();       // all waves done reading buffer b
    if (s + 3 < MSTEPS) issue(s + 3, b);

    floatx4 acc[4];
#pragma unroll
    for (int nf = 0; nf < 4; ++nf) acc[nf] = (floatx4){0.f, 0.f, 0.f, 0.f};
#pragma unroll
    for (int kw = 0; kw < 8; ++kw)
#pragma unroll
      for (int nf = 0; nf < 4; ++nf)
        acc[nf] = __builtin_amdgcn_mfma_f32_16x16x32_bf16(av[kw], Bf[kw][nf], acc[nf], 0, 0, 0);

    const int m0 = mbase + s * 16;
#pragma unroll
    for (int nf = 0; nf < 4; ++nf) {
      float* op = out + (size_t)(m0 + r0) * LDX + col0 + nf * 16;
#pragma unroll
      for (int r = 0; r < 4; ++r) op[(size_t)r * LDX] = acc[nf][r];
    }
  }
}

// Fallback (ws too small): one-kernel fused path, tanh applied during B staging.
__global__ __launch_bounds__(256) void bdgemm_fused(const float* __restrict__ x,
                                                    const float* __restrict__ blocks,
                                                    float* __restrict__ out) {
  __shared__ unsigned short As[64 * 32];
  __shared__ unsigned short Bs[256 * 40];
  const int t = threadIdx.x;
  const int lane = t & 63;
  const int wave = t >> 6;
  const int mtile = blockIdx.x;
  const int j = blockIdx.y;
  const int m0 = mtile * 64;
  const float* xg = x + (size_t)m0 * LDX + j * BS;
  const int srow = t >> 2;
  const int scol = (t & 3) * 8;
  const int wn = wave * 64;
  const int fr = lane & 15;
  const int fq = (lane >> 4) * 8;

  floatx4 acc[4][4];
#pragma unroll
  for (int a = 0; a < 4; ++a)
#pragma unroll
    for (int b = 0; b < 4; ++b) acc[a][b] = (floatx4){0.f, 0.f, 0.f, 0.f};

  for (int kt = 0; kt < 8; ++kt) {
    const int k0 = kt * 32;
    const float* ap = xg + (size_t)srow * LDX + k0 + scol;
    float4 a0 = *(const float4*)(ap);
    float4 a1 = *(const float4*)(ap + 4);
    uint4 pk;
    pk.x = f2bf(a0.x) | (f2bf(a0.y) << 16);
    pk.y = f2bf(a0.z) | (f2bf(a0.w) << 16);
    pk.z = f2bf(a1.x) | (f2bf(a1.y) << 16);
    pk.w = f2bf(a1.z) | (f2bf(a1.w) << 16);
    *(uint4*)(As + t * 8) = pk;
#pragma unroll
    for (int i = 0; i < 32; ++i) {
      const int idx = i * 256 + t;
      const int kk = idx >> 8;
      const int nn = idx & 255;
      float v = tanhf(blocks[(size_t)(j * BS + k0 + kk) * LDX + j * BS + nn]);
      Bs[nn * 40 + kk] = (unsigned short)f2bf(v);
    }
    __syncthreads();
    bf16x8 af[4], bfm[4];
#pragma unroll
    for (int i = 0; i < 4; ++i) {
      af[i] = *(const bf16x8*)(As + (i * 16 + fr) * 32 + fq);
      bfm[i] = *(const bf16x8*)(Bs + (wn + i * 16 + fr) * 40 + fq);
    }
#pragma unroll
    for (int mi = 0; mi < 4; ++mi)
#pragma unroll
      for (int ni = 0; ni < 4; ++ni)
        acc[mi][ni] =
            __builtin_amdgcn_mfma_f32_16x16x32_bf16(af[mi], bfm[ni], acc[mi][ni], 0, 0, 0);
    __syncthreads();
  }
  const int r0 = (lane >> 4) * 4;
  const int ocol = j * BS + wn + fr;
#pragma unroll
  for (int mi = 0; mi < 4; ++mi)
#pragma unroll
    for (int ni = 0; ni < 4; ++ni) {
      float* op = out + (size_t)(m0 + mi * 16 + r0) * LDX + ocol + ni * 16;
#pragma unroll
      for (int r = 0; r < 4; ++r) op[(size_t)r * LDX] = acc[mi][ni][r];
    }
}

extern "C" void kernel_launch(void* const* d_in, const int* in_sizes, int n_in,
                              void* d_out, int out_size, void* d_ws, size_t ws_size,
                              hipStream_t stream) {
  const float* x = (const float*)d_in[0];       // 8192x4096 f32
  const float* blocks = (const float*)d_in[1];  // 4096x4096 f32
  // d_in[2] (mask) unused: block structure static, tanh(0)=0.
  float* out = (float*)d_out;

  const size_t need = (size_t)NBLK * BS * BS * sizeof(unsigned short);  // 2 MB
  if (d_ws != nullptr && ws_size >= need) {
    unsigned short* wsT = (unsigned short*)d_ws;
    tanh_pack<<<dim3(4, 4, NBLK), 256, 0, stream>>>(blocks, wsT);
    bdgemm_pipe<<<dim3(WPJ, NBLK), 256, 0, stream>>>(x, wsT, out);
  } else {
    bdgemm_fused<<<dim3(128, NBLK), 256, 0, stream>>>(x, blocks, out);
  }
}